// Round 1
// baseline (71.505 us; speedup 1.0000x reference)
//
#include <hip/hip_runtime.h>

// AllZeroDigitalFilter: time-varying FIR with linearly-interpolated coefficients.
//   out[b,t] = sum_{k=0..255} x[b,t-k] * ((1-f)*h[b,n,k] + f*h[b,n1,k])
//   n = t/80, f = (t%80)/80, n1 = min(n+1, N-1), x[neg] = 0
// B=8, N=800, P=80, T=64000, TAPS=256.

#define TAPS 256
#define PP 80
#define BB 8
#define NN 800
#define TT (NN * PP)
#define FPB 8            // frames per block
#define TPF 16           // threads per frame
#define RR 5             // outputs per thread (TPF*RR == PP)
#define NTHREADS (FPB * TPF)   // 128
#define HSTRIDE 260      // 256 + 4: shifts each frame-row by 4 banks
#define XWIN (FPB * PP + TAPS - 1)   // 895
#define CHUNKS (NN / FPB)            // 100

__global__ __launch_bounds__(NTHREADS) void azdf_kernel(
    const float* __restrict__ x, const float* __restrict__ h,
    float* __restrict__ out)
{
    __shared__ float sh[(FPB + 1) * HSTRIDE];   // 9360 B
    __shared__ float sx[XWIN + 1];              // 3584 B

    const int tid = threadIdx.x;
    const int blk = blockIdx.x;
    const int b   = blk / CHUNKS;
    const int nc  = blk % CHUNKS;
    const int n0  = nc * FPB;
    const int t0  = n0 * PP;

    // ---- stage h rows n0 .. n0+FPB (clamped to N-1), float4 loads ----
    const float* hb = h + (size_t)b * NN * TAPS;
    for (int i4 = tid; i4 < (FPB + 1) * (TAPS / 4); i4 += NTHREADS) {
        int r  = i4 >> 6;          // row 0..8
        int k4 = i4 & 63;          // float4 index within row
        int gr = n0 + r;
        if (gr > NN - 1) gr = NN - 1;
        float4 v = ((const float4*)(hb + (size_t)gr * TAPS))[k4];
        ((float4*)(sh + r * HSTRIDE))[k4] = v;
    }

    // ---- stage x window x[t0-255 .. t0+640) ----
    const float* xb = x + (size_t)b * TT;
    for (int i = tid; i < XWIN; i += NTHREADS) {
        int g = t0 - (TAPS - 1) + i;
        sx[i] = (g >= 0) ? xb[g] : 0.0f;
    }
    __syncthreads();

    // ---- compute: each thread does RR consecutive outputs of one frame ----
    const int lf   = tid / TPF;        // local frame 0..7
    const int lane = tid % TPF;        // 0..15
    const int p0   = lane * RR;        // phase of first output
    const float* h0 = sh + lf * HSTRIDE;
    const float* h1 = h0 + HSTRIDE;
    const int base = lf * PP + p0 + (TAPS - 1);  // sx index of x[t] for r=0

    float acc0[RR], acc1[RR];
    #pragma unroll
    for (int r = 0; r < RR; ++r) { acc0[r] = 0.0f; acc1[r] = 0.0f; }

    for (int k = 0; k < TAPS; k += 4) {
        // x register window covering taps k..k+3 for all RR outputs
        float xv[RR + 3];
        #pragma unroll
        for (int j = 0; j < RR + 3; ++j) xv[j] = sx[base - k - 3 + j];
        #pragma unroll
        for (int d = 0; d < 4; ++d) {
            float c0 = h0[k + d];
            float c1 = h1[k + d];
            #pragma unroll
            for (int r = 0; r < RR; ++r) {
                float xr = xv[r + 3 - d];   // == sx[base + r - (k+d)]
                acc0[r] = fmaf(xr, c0, acc0[r]);
                acc1[r] = fmaf(xr, c1, acc1[r]);
            }
        }
    }

    float* ob = out + (size_t)b * TT + t0 + lf * PP + p0;
    #pragma unroll
    for (int r = 0; r < RR; ++r) {
        float f = (float)(p0 + r) * (1.0f / PP);
        ob[r] = acc0[r] + f * (acc1[r] - acc0[r]);
    }
}

extern "C" void kernel_launch(void* const* d_in, const int* in_sizes, int n_in,
                              void* d_out, int out_size, void* d_ws, size_t ws_size,
                              hipStream_t stream) {
    const float* x = (const float*)d_in[0];
    const float* h = (const float*)d_in[1];
    float* out    = (float*)d_out;
    azdf_kernel<<<BB * CHUNKS, NTHREADS, 0, stream>>>(x, h, out);
}